// Round 5
// baseline (285.131 us; speedup 1.0000x reference)
//
#include <hip/hip_runtime.h>

constexpr int D_IN = 20;   // input feature dim
constexpr int HP   = 16;   // projection dim
constexpr int K    = 6;    // neighbors
constexpr int SAMP = 512;  // threshold sample size
constexpr int CAP  = 768;  // per-row candidate buffer capacity

// Sequential fmaf dot — MUST be bit-identical across thresh/scan/final.
__device__ __forceinline__ float dot16_seq(const float4* q, const float4* c) {
  float s = 0.f;
#pragma unroll
  for (int m = 0; m < 4; ++m) {
    s = fmaf(q[m].x, c[m].x, s);
    s = fmaf(q[m].y, c[m].y, s);
    s = fmaf(q[m].z, c[m].z, s);
    s = fmaf(q[m].w, c[m].w, s);
  }
  return s;
}

// ---------------- projection + row-normalize + counter zeroing ----------------
__global__ void k_proj(const float* __restrict__ x, const float* __restrict__ Wp,
                       const float* __restrict__ bp, float* __restrict__ hn,
                       float* __restrict__ insum, int* __restrict__ indeg,
                       int* __restrict__ cnt, int N) {
  int i = blockIdx.x * blockDim.x + threadIdx.x;
  if (i >= N) return;
  insum[i] = 0.f; indeg[i] = 0; cnt[i] = 0;
  float xr[D_IN];
#pragma unroll
  for (int d = 0; d < D_IN; ++d) xr[d] = x[i*D_IN + d];
  float hv[HP];
  float nrm2 = 0.f;
#pragma unroll
  for (int h = 0; h < HP; ++h) {
    float a = bp[h];
#pragma unroll
    for (int d = 0; d < D_IN; ++d) a += xr[d] * Wp[d*HP + h];
    hv[h] = a;
    nrm2 += a * a;
  }
  float inv = 1.f / fmaxf(sqrtf(nrm2), 1e-12f);
#pragma unroll
  for (int h = 0; h < HP; ++h) hn[i*HP + h] = hv[h] * inv;
}

// ---------------- per-lane top-6 in NAMED registers ----
struct Top6 { float v0,v1,v2,v3,v4,v5; int i0,i1,i2,i3,i4,i5; };

__device__ __forceinline__ void t6_init(Top6& t) {
  t.v0=t.v1=t.v2=t.v3=t.v4=t.v5=-1e30f;
  t.i0=t.i1=t.i2=t.i3=t.i4=t.i5=-1;
}

#define T6_SWAP(a,b,ia,ib) { float tv=a; a=b; b=tv; int ti=ia; ia=ib; ib=ti; }

__device__ __forceinline__ void t6_insert(Top6& t, float s, int c) {
  if (s > t.v5) {
    t.v5 = s; t.i5 = c;
    if (t.v5 > t.v4) { T6_SWAP(t.v4, t.v5, t.i4, t.i5); }
    if (t.v4 > t.v3) { T6_SWAP(t.v3, t.v4, t.i3, t.i4); }
    if (t.v3 > t.v2) { T6_SWAP(t.v2, t.v3, t.i2, t.i3); }
    if (t.v2 > t.v1) { T6_SWAP(t.v1, t.v2, t.i1, t.i2); }
    if (t.v1 > t.v0) { T6_SWAP(t.v0, t.v1, t.i0, t.i1); }
  }
}

// lane-local argmax over the 6 named slots, (val desc, idx asc); empty (i=-1) loses ties
__device__ __forceinline__ void t6_best(const Top6& t, float& cv, int& ci) {
  cv = t.v0; ci = t.i0;
  if (t.v1 > cv || (t.v1 == cv && (unsigned)t.i1 < (unsigned)ci)) { cv = t.v1; ci = t.i1; }
  if (t.v2 > cv || (t.v2 == cv && (unsigned)t.i2 < (unsigned)ci)) { cv = t.v2; ci = t.i2; }
  if (t.v3 > cv || (t.v3 == cv && (unsigned)t.i3 < (unsigned)ci)) { cv = t.v3; ci = t.i3; }
  if (t.v4 > cv || (t.v4 == cv && (unsigned)t.i4 < (unsigned)ci)) { cv = t.v4; ci = t.i4; }
  if (t.v5 > cv || (t.v5 == cv && (unsigned)t.i5 < (unsigned)ci)) { cv = t.v5; ci = t.i5; }
}

__device__ __forceinline__ void t6_consume(Top6& t, int mi) {
  if (t.i0 == mi) t.v0 = -1e30f;
  if (t.i1 == mi) t.v1 = -1e30f;
  if (t.i2 == mi) t.v2 = -1e30f;
  if (t.i3 == mi) t.v3 = -1e30f;
  if (t.i4 == mi) t.v4 = -1e30f;
  if (t.i5 == mi) t.v5 = -1e30f;
}

// ---------------- threshold pass: exact 6th-largest over SAMP-sample, wave per row
__global__ __launch_bounds__(256) void k_thresh(const float* __restrict__ hn,
                                                float* __restrict__ tau, int N) {
  int wave = threadIdx.x >> 6, lane = threadIdx.x & 63;
  int row = blockIdx.x * 4 + wave;
  const float4* hn4 = (const float4*)hn;
  float4 q[4];
#pragma unroll
  for (int m = 0; m < 4; ++m) q[m] = hn4[(size_t)row*4 + m];
  Top6 t; t6_init(t);
#pragma unroll
  for (int k = 0; k < SAMP/64; ++k) {
    int c = lane + 64*k;
    if (c != row) {
      float4 cv[4];
#pragma unroll
      for (int m = 0; m < 4; ++m) cv[m] = hn4[(size_t)c*4 + m];
      float s = dot16_seq(q, cv);
      t6_insert(t, s, c);
    }
  }
  float last = -1e30f;
  for (int sel = 0; sel < K; ++sel) {
    float cv; int ci;
    t6_best(t, cv, ci);
    float mv = cv; int mi = ci;
#pragma unroll
    for (int m = 1; m < 64; m <<= 1) {
      float ov = __shfl_xor(mv, m);
      int   oi = __shfl_xor(mi, m);
      if (ov > mv || (ov == mv && (unsigned)oi < (unsigned)mi)) { mv = ov; mi = oi; }
    }
    t6_consume(t, mi);
    last = mv;
  }
  if (lane == 0) tau[row] = last;
}

// ---------------- stateless threshold scan: 32 rows x 1024 cols per block ----
// Candidates: 4/lane in NAMED float4s (never address-taken -> stay in VGPRs).
// Queries: wave-uniform scalar loads (SGPR broadcast).
#define DOT16(S, C0, C1, C2, C3)                                   \
  S = fmaf(q0,  C0.x, S); S = fmaf(q1,  C0.y, S);                  \
  S = fmaf(q2,  C0.z, S); S = fmaf(q3,  C0.w, S);                  \
  S = fmaf(q4,  C1.x, S); S = fmaf(q5,  C1.y, S);                  \
  S = fmaf(q6,  C1.z, S); S = fmaf(q7,  C1.w, S);                  \
  S = fmaf(q8,  C2.x, S); S = fmaf(q9,  C2.y, S);                  \
  S = fmaf(q10, C2.z, S); S = fmaf(q11, C2.w, S);                  \
  S = fmaf(q12, C3.x, S); S = fmaf(q13, C3.y, S);                  \
  S = fmaf(q14, C3.z, S); S = fmaf(q15, C3.w, S);

__global__ __launch_bounds__(256) void k_scan2(
    const float* __restrict__ hn, const float* __restrict__ tau,
    int* __restrict__ cnt, unsigned short* __restrict__ buf, int N) {
  int ib = blockIdx.x >> 3;          // row-block (N/32 of them)
  int jc = blockIdx.x & 7;           // col-chunk of 1024
  int ibase = ib * 32;
  int wave = threadIdx.x >> 6, lane = threadIdx.x & 63;
  const float4* hn4 = (const float4*)hn;

  int jb = jc*1024 + wave*256 + lane;   // lane's cands: jb, jb+64, jb+128, jb+192
  float4 cA0 = hn4[(size_t)(jb      )*4+0], cA1 = hn4[(size_t)(jb      )*4+1],
         cA2 = hn4[(size_t)(jb      )*4+2], cA3 = hn4[(size_t)(jb      )*4+3];
  float4 cB0 = hn4[(size_t)(jb +  64)*4+0], cB1 = hn4[(size_t)(jb +  64)*4+1],
         cB2 = hn4[(size_t)(jb +  64)*4+2], cB3 = hn4[(size_t)(jb +  64)*4+3];
  float4 cC0 = hn4[(size_t)(jb + 128)*4+0], cC1 = hn4[(size_t)(jb + 128)*4+1],
         cC2 = hn4[(size_t)(jb + 128)*4+2], cC3 = hn4[(size_t)(jb + 128)*4+3];
  float4 cD0 = hn4[(size_t)(jb + 192)*4+0], cD1 = hn4[(size_t)(jb + 192)*4+1],
         cD2 = hn4[(size_t)(jb + 192)*4+2], cD3 = hn4[(size_t)(jb + 192)*4+3];

#pragma unroll 2
  for (int ii = 0; ii < 32; ++ii) {
    int ig = ibase + ii;
    const float* qp = hn + (size_t)ig * HP;   // uniform -> s_load
    float tau_i = tau[ig];                    // uniform -> s_load
    float q0 = qp[0],  q1 = qp[1],  q2 = qp[2],  q3 = qp[3],
          q4 = qp[4],  q5 = qp[5],  q6 = qp[6],  q7 = qp[7],
          q8 = qp[8],  q9 = qp[9],  q10 = qp[10], q11 = qp[11],
          q12 = qp[12], q13 = qp[13], q14 = qp[14], q15 = qp[15];
    float sA = 0.f, sB = 0.f, sC = 0.f, sD = 0.f;
    DOT16(sA, cA0, cA1, cA2, cA3)
    DOT16(sB, cB0, cB1, cB2, cB3)
    DOT16(sC, cC0, cC1, cC2, cC3)
    DOT16(sD, cD0, cD1, cD2, cD3)
    // self-hit allowed (s_ii≈1>=tau); k_final filters j==row
    if (sA >= tau_i) {
      int pos = atomicAdd(&cnt[ig], 1);
      if (pos < CAP) buf[(size_t)ig*CAP + pos] = (unsigned short)jb;
    }
    if (sB >= tau_i) {
      int pos = atomicAdd(&cnt[ig], 1);
      if (pos < CAP) buf[(size_t)ig*CAP + pos] = (unsigned short)(jb + 64);
    }
    if (sC >= tau_i) {
      int pos = atomicAdd(&cnt[ig], 1);
      if (pos < CAP) buf[(size_t)ig*CAP + pos] = (unsigned short)(jb + 128);
    }
    if (sD >= tau_i) {
      int pos = atomicAdd(&cnt[ig], 1);
      if (pos < CAP) buf[(size_t)ig*CAP + pos] = (unsigned short)(jb + 192);
    }
  }
}

// ---------------- exact top-6 from buffered candidates, wave per row ----
__global__ __launch_bounds__(256) void k_final(
    const float* __restrict__ hn, const unsigned short* __restrict__ buf,
    const int* __restrict__ cnt,
    float* __restrict__ evals, int* __restrict__ eidx,
    float* __restrict__ ownsum, float* insum, int* indeg, int N) {
  int wave = threadIdx.x >> 6, lane = threadIdx.x & 63;
  int row = blockIdx.x * 4 + wave;
  const float4* hn4 = (const float4*)hn;
  float4 q[4];
#pragma unroll
  for (int m = 0; m < 4; ++m) q[m] = hn4[(size_t)row*4 + m];
  int n = min(cnt[row], CAP);
  Top6 t; t6_init(t);
  for (int e = lane; e < n; e += 64) {
    int j = buf[(size_t)row*CAP + e];
    if (j != row) {
      float4 cv[4];
#pragma unroll
      for (int m = 0; m < 4; ++m) cv[m] = hn4[(size_t)j*4 + m];
      float s = dot16_seq(q, cv);
      t6_insert(t, s, j);
    }
  }
  float osum = 0.f;
  for (int sel = 0; sel < K; ++sel) {
    float cv; int ci;
    t6_best(t, cv, ci);
    float mv = cv; int mi = ci;
#pragma unroll
    for (int m = 1; m < 64; m <<= 1) {
      float ov = __shfl_xor(mv, m);
      int   oi = __shfl_xor(mi, m);
      if (ov > mv || (ov == mv && (unsigned)oi < (unsigned)mi)) { mv = ov; mi = oi; }
    }
    t6_consume(t, mi);
    if (lane == 0) {
      evals[row*K + sel] = mv;
      eidx [row*K + sel] = mi;
      osum += mv;
      atomicAdd(&insum[mi], mv);
      atomicAdd(&indeg[mi], 1);
    }
  }
  if (lane == 0) ownsum[row] = osum;
}

// ------- fused: degree scalars + exclusive scan of (K + indeg) -> CSR offsets ----
__global__ __launch_bounds__(1024) void k_scan(
    const int* __restrict__ indeg, const float* __restrict__ ownsum,
    const float* __restrict__ insum,
    float* __restrict__ rnorm, float* __restrict__ dinv, float* __restrict__ selfc,
    int* __restrict__ cursor, int* __restrict__ offsets, int N) {
  __shared__ int sums[1024];
  int tid = threadIdx.x;
  int per = N >> 10;           // assumes N multiple of 1024
  int base = tid * per;
  int loc[16];
  int s = 0;
  for (int k = 0; k < per; ++k) {
    int i = base + k;
    float rs = 0.5f * (ownsum[i] + insum[i]);
    float rn = 1.f / (rs + 1e-8f);
    float ds = 1.f + rs * rn;
    float di = rsqrtf(fmaxf(ds, 1e-12f));
    rnorm[i] = rn; dinv[i] = di; selfc[i] = di * di; cursor[i] = 0;
    loc[k] = s; s += K + indeg[i];
  }
  sums[tid] = s;
  __syncthreads();
  for (int d = 1; d < 1024; d <<= 1) {
    int v = (tid >= d) ? sums[tid - d] : 0;
    __syncthreads();
    sums[tid] += v;
    __syncthreads();
  }
  int excl = (tid == 0) ? 0 : sums[tid - 1];
  for (int k = 0; k < per; ++k) offsets[base + k] = excl + loc[k];
  if (tid == 1023) offsets[N] = sums[1023];
}

// ---------------- fill symmetrized CSR with fused coefficients ----------------
__global__ void k_fill(const float* __restrict__ evals, const int* __restrict__ eidx,
                       const float* __restrict__ rnorm, const float* __restrict__ dinv,
                       const int* __restrict__ offsets, int* cursor,
                       int* __restrict__ col, float* __restrict__ coef, int N) {
  int e = blockIdx.x * blockDim.x + threadIdx.x;
  if (e >= N * K) return;
  int i = e / K;
  int j = eidx[e];
  float v = evals[e];
  float base = 0.5f * v * dinv[i] * dinv[j];
  int p = atomicAdd(&cursor[i], 1);
  col [offsets[i] + p] = j;
  coef[offsets[i] + p] = base * rnorm[i];
  int q = atomicAdd(&cursor[j], 1);
  col [offsets[j] + q] = i;
  coef[offsets[j] + q] = base * rnorm[j];
}

// ---- fully fused layer: on-the-fly XW + sparse gather + LN + relu + MLP residual
// LPR lanes per row; DOUT<=32 packs 2 rows per wave.
template<int DIN, int HID, int DOUT>
__global__ __launch_bounds__(256) void k_gfused(
    const float* __restrict__ hprev,
    const int* __restrict__ offsets, const int* __restrict__ col,
    const float* __restrict__ coef, const float* __restrict__ selfc,
    const float* __restrict__ W, const float* __restrict__ b,
    const float* __restrict__ g, const float* __restrict__ bt,
    const float* __restrict__ w0, const float* __restrict__ b0,
    const float* __restrict__ w1, const float* __restrict__ b1,
    float* __restrict__ out, int N) {
  constexpr int LPR = (DOUT <= 32) ? 32 : 64;   // lanes per row
  constexpr int RPW = 64 / LPR;                  // rows per wave
  __shared__ float hid_s[4*RPW][HID];
  int wave = threadIdx.x >> 6;
  int lane = threadIdx.x & 63;
  int sub  = lane / LPR;
  int ol   = lane % LPR;
  int row  = (blockIdx.x * 4 + wave) * RPW + sub;
  int slot = wave * RPW + sub;

  // GCN weight columns in registers
  float wc0[DIN];
#pragma unroll
  for (int d = 0; d < DIN; ++d) wc0[d] = W[d*DOUT + ol];
  float wc1[(DOUT > 64) ? DIN : 1];
  if constexpr (DOUT > 64) {
#pragma unroll
    for (int d = 0; d < DIN; ++d) wc1[d] = W[d*DOUT + ol + 64];
  }

  // self term + sparse neighbor accumulation (XW computed on the fly)
  float acc0, acc1 = 0.f;
  {
    const float* hj = hprev + (size_t)row * DIN;
    float c = selfc[row];
    float t0 = 0.f, t1 = 0.f;
#pragma unroll
    for (int d = 0; d < DIN; ++d) {
      float hd = hj[d];
      t0 = fmaf(hd, wc0[d], t0);
      if constexpr (DOUT > 64) t1 = fmaf(hd, wc1[d], t1);
    }
    acc0 = c * t0;
    if constexpr (DOUT > 64) acc1 = c * t1;
  }
  int pe = offsets[row + 1];
  for (int p = offsets[row]; p < pe; ++p) {
    int j = col[p]; float cf = coef[p];
    const float* hj = hprev + (size_t)j * DIN;
    float t0 = 0.f, t1 = 0.f;
#pragma unroll
    for (int d = 0; d < DIN; ++d) {
      float hd = hj[d];
      t0 = fmaf(hd, wc0[d], t0);
      if constexpr (DOUT > 64) t1 = fmaf(hd, wc1[d], t1);
    }
    acc0 = fmaf(cf, t0, acc0);
    if constexpr (DOUT > 64) acc1 = fmaf(cf, t1, acc1);
  }
  float u0 = acc0 + b[ol];
  float u1 = (DOUT > 64) ? acc1 + b[ol + 64] : 0.f;

  // LayerNorm over DOUT, reduce across the LPR-lane group
  float s = u0 + u1;
#pragma unroll
  for (int m = 1; m < LPR; m <<= 1) s += __shfl_xor(s, m);
  float mean = s / (float)DOUT;
  float d0 = u0 - mean;
  float d1 = (DOUT > 64) ? u1 - mean : 0.f;
  float vs = d0*d0 + d1*d1;
#pragma unroll
  for (int m = 1; m < LPR; m <<= 1) vs += __shfl_xor(vs, m);
  float rstd = rsqrtf(vs / (float)DOUT + 1e-5f);
  float t0v = fmaxf(d0*rstd*g[ol] + bt[ol], 0.f);
  float t1v = (DOUT > 64) ? fmaxf(d1*rstd*g[ol+64] + bt[ol+64], 0.f) : 0.f;

  // MLP hidden = relu(hprev @ w0 + b0) -> LDS (lane computes HID/LPR cols)
  float hp[DIN];
#pragma unroll
  for (int d = 0; d < DIN; ++d) hp[d] = hprev[(size_t)row*DIN + d];
  {
    float a = b0[ol];
#pragma unroll
    for (int d = 0; d < DIN; ++d) a = fmaf(hp[d], w0[d*HID + ol], a);
    hid_s[slot][ol] = fmaxf(a, 0.f);
  }
  if constexpr (HID > LPR) {
    float a = b0[ol + LPR];
#pragma unroll
    for (int d = 0; d < DIN; ++d) a = fmaf(hp[d], w0[d*HID + ol + LPR], a);
    hid_s[slot][ol + LPR] = fmaxf(a, 0.f);
  }
  __syncthreads();

  {
    float a = b1[ol];
    for (int h = 0; h < HID; ++h) a = fmaf(hid_s[slot][h], w1[h*DOUT + ol], a);
    out[(size_t)row*DOUT + ol] = t0v + a;
  }
  if constexpr (DOUT > 64) {
    float a = b1[ol + 64];
    for (int h = 0; h < HID; ++h) a = fmaf(hid_s[slot][h], w1[h*DOUT + ol + 64], a);
    out[(size_t)row*DOUT + ol + 64] = t1v + a;
  }
}

extern "C" void kernel_launch(void* const* d_in, const int* in_sizes, int n_in,
                              void* d_out, int out_size, void* d_ws, size_t ws_size,
                              hipStream_t stream) {
  const float* x    = (const float*)d_in[0];
  const float* Wp   = (const float*)d_in[1];
  const float* bp   = (const float*)d_in[2];
  const float* gw0  = (const float*)d_in[3];
  const float* gb0  = (const float*)d_in[4];
  const float* gw1  = (const float*)d_in[5];
  const float* gb1  = (const float*)d_in[6];
  const float* gw2  = (const float*)d_in[7];
  const float* gb2  = (const float*)d_in[8];
  const float* lg0  = (const float*)d_in[9];
  const float* lb0  = (const float*)d_in[10];
  const float* lg1  = (const float*)d_in[11];
  const float* lb1  = (const float*)d_in[12];
  const float* lg2  = (const float*)d_in[13];
  const float* lb2  = (const float*)d_in[14];
  const float* riw0 = (const float*)d_in[15];
  const float* rib0 = (const float*)d_in[16];
  const float* riw1 = (const float*)d_in[17];
  const float* rib1 = (const float*)d_in[18];
  const float* rhw0 = (const float*)d_in[19];
  const float* rhb0 = (const float*)d_in[20];
  const float* rhw1 = (const float*)d_in[21];
  const float* rhb1 = (const float*)d_in[22];
  const float* row0 = (const float*)d_in[23];
  const float* rob0 = (const float*)d_in[24];
  const float* row1 = (const float*)d_in[25];
  const float* rob1 = (const float*)d_in[26];
  int N = in_sizes[0] / D_IN;   // 8192
  float* out = (float*)d_out;

  char* ws = (char*)d_ws;
  size_t off = 0;
  auto alloc = [&](size_t bytes) -> void* {
    void* p = ws + off;
    off += (bytes + 255) & ~(size_t)255;
    return p;
  };
  float* hn      = (float*)alloc((size_t)N * HP * 4);
  float* evals   = (float*)alloc((size_t)N * K * 4);
  int*   eidx    = (int*)  alloc((size_t)N * K * 4);
  float* ownsum  = (float*)alloc((size_t)N * 4);
  float* insum   = (float*)alloc((size_t)N * 4);
  int*   indeg   = (int*)  alloc((size_t)N * 4);
  float* rnorm   = (float*)alloc((size_t)N * 4);
  float* dinv    = (float*)alloc((size_t)N * 4);
  float* selfc   = (float*)alloc((size_t)N * 4);
  int*   offsets = (int*)  alloc((size_t)(N + 1) * 4);
  int*   cursor  = (int*)  alloc((size_t)N * 4);
  int*   colA    = (int*)  alloc((size_t)N * K * 2 * 4);
  float* coefA   = (float*)alloc((size_t)N * K * 2 * 4);
  float* h1      = (float*)alloc((size_t)N * 32 * 4);
  float* h2      = (float*)alloc((size_t)N * 32 * 4);
  float* tau     = (float*)alloc((size_t)N * 4);
  int*   cnt     = (int*)  alloc((size_t)N * 4);
  unsigned short* buf = (unsigned short*)alloc((size_t)N * CAP * 2);
  (void)ws_size; (void)n_in; (void)out_size;

  const int B = 256;
  hipLaunchKernelGGL(k_proj, dim3((N + B - 1) / B), dim3(B), 0, stream,
                     x, Wp, bp, hn, insum, indeg, cnt, N);
  hipLaunchKernelGGL(k_thresh, dim3(N / 4), dim3(B), 0, stream, hn, tau, N);
  // (N/32) row-blocks x 8 col-chunks of 1024
  hipLaunchKernelGGL(k_scan2, dim3((N / 32) * 8), dim3(B), 0, stream, hn, tau, cnt, buf, N);
  hipLaunchKernelGGL(k_final, dim3(N / 4), dim3(B), 0, stream,
                     hn, buf, cnt, evals, eidx, ownsum, insum, indeg, N);
  hipLaunchKernelGGL(k_scan, dim3(1), dim3(1024), 0, stream,
                     indeg, ownsum, insum, rnorm, dinv, selfc, cursor, offsets, N);
  hipLaunchKernelGGL(k_fill, dim3((N * K + B - 1) / B), dim3(B), 0, stream,
                     evals, eidx, rnorm, dinv, offsets, cursor, colA, coefA, N);

  // layer 0: x[20] -> 32   (2 rows/wave, 8 rows/block)
  hipLaunchKernelGGL((k_gfused<20, 32, 32>), dim3(N / 8), dim3(B), 0, stream,
                     x, offsets, colA, coefA, selfc, gw0, gb0, lg0, lb0,
                     riw0, rib0, riw1, rib1, h1, N);
  // layer 1: h1[32] -> 32
  hipLaunchKernelGGL((k_gfused<32, 32, 32>), dim3(N / 8), dim3(B), 0, stream,
                     h1, offsets, colA, coefA, selfc, gw1, gb1, lg1, lb1,
                     rhw0, rhb0, rhw1, rhb1, h2, N);
  // layer 2: h2[32] -> 128  (1 row/wave, 4 rows/block)
  hipLaunchKernelGGL((k_gfused<32, 128, 128>), dim3(N / 4), dim3(B), 0, stream,
                     h2, offsets, colA, coefA, selfc, gw2, gb2, lg2, lb2,
                     row0, rob0, row1, rob1, out, N);
}

// Round 6
// 245.519 us; speedup vs baseline: 1.1613x; 1.1613x over previous
//
#include <hip/hip_runtime.h>

constexpr int D_IN = 20;   // input feature dim
constexpr int HP   = 16;   // projection dim
constexpr int K    = 6;    // neighbors
constexpr int SAMP = 512;  // threshold sample size
constexpr int CAP  = 768;  // per-row candidate buffer capacity

// Sequential fmaf dot — MUST be bit-identical across thresh/scan/final.
__device__ __forceinline__ float dot16_seq(const float4* q, const float4* c) {
  float s = 0.f;
#pragma unroll
  for (int m = 0; m < 4; ++m) {
    s = fmaf(q[m].x, c[m].x, s);
    s = fmaf(q[m].y, c[m].y, s);
    s = fmaf(q[m].z, c[m].z, s);
    s = fmaf(q[m].w, c[m].w, s);
  }
  return s;
}

// ---------------- projection + row-normalize + counter zeroing ----------------
__global__ void k_proj(const float* __restrict__ x, const float* __restrict__ Wp,
                       const float* __restrict__ bp, float* __restrict__ hn,
                       float* __restrict__ insum, int* __restrict__ indeg,
                       int* __restrict__ cnt, int N) {
  int i = blockIdx.x * blockDim.x + threadIdx.x;
  if (i >= N) return;
  insum[i] = 0.f; indeg[i] = 0; cnt[i] = 0;
  float xr[D_IN];
#pragma unroll
  for (int d = 0; d < D_IN; ++d) xr[d] = x[i*D_IN + d];
  float hv[HP];
  float nrm2 = 0.f;
#pragma unroll
  for (int h = 0; h < HP; ++h) {
    float a = bp[h];
#pragma unroll
    for (int d = 0; d < D_IN; ++d) a += xr[d] * Wp[d*HP + h];
    hv[h] = a;
    nrm2 += a * a;
  }
  float inv = 1.f / fmaxf(sqrtf(nrm2), 1e-12f);
#pragma unroll
  for (int h = 0; h < HP; ++h) hn[i*HP + h] = hv[h] * inv;
}

// ---------------- per-lane top-6 in NAMED registers ----
struct Top6 { float v0,v1,v2,v3,v4,v5; int i0,i1,i2,i3,i4,i5; };

__device__ __forceinline__ void t6_init(Top6& t) {
  t.v0=t.v1=t.v2=t.v3=t.v4=t.v5=-1e30f;
  t.i0=t.i1=t.i2=t.i3=t.i4=t.i5=-1;
}

#define T6_SWAP(a,b,ia,ib) { float tv=a; a=b; b=tv; int ti=ia; ia=ib; ib=ti; }

__device__ __forceinline__ void t6_insert(Top6& t, float s, int c) {
  if (s > t.v5) {
    t.v5 = s; t.i5 = c;
    if (t.v5 > t.v4) { T6_SWAP(t.v4, t.v5, t.i4, t.i5); }
    if (t.v4 > t.v3) { T6_SWAP(t.v3, t.v4, t.i3, t.i4); }
    if (t.v3 > t.v2) { T6_SWAP(t.v2, t.v3, t.i2, t.i3); }
    if (t.v2 > t.v1) { T6_SWAP(t.v1, t.v2, t.i1, t.i2); }
    if (t.v1 > t.v0) { T6_SWAP(t.v0, t.v1, t.i0, t.i1); }
  }
}

// lane-local argmax over the 6 named slots, (val desc, idx asc); empty (i=-1) loses ties
__device__ __forceinline__ void t6_best(const Top6& t, float& cv, int& ci) {
  cv = t.v0; ci = t.i0;
  if (t.v1 > cv || (t.v1 == cv && (unsigned)t.i1 < (unsigned)ci)) { cv = t.v1; ci = t.i1; }
  if (t.v2 > cv || (t.v2 == cv && (unsigned)t.i2 < (unsigned)ci)) { cv = t.v2; ci = t.i2; }
  if (t.v3 > cv || (t.v3 == cv && (unsigned)t.i3 < (unsigned)ci)) { cv = t.v3; ci = t.i3; }
  if (t.v4 > cv || (t.v4 == cv && (unsigned)t.i4 < (unsigned)ci)) { cv = t.v4; ci = t.i4; }
  if (t.v5 > cv || (t.v5 == cv && (unsigned)t.i5 < (unsigned)ci)) { cv = t.v5; ci = t.i5; }
}

__device__ __forceinline__ void t6_consume(Top6& t, int mi) {
  if (t.i0 == mi) t.v0 = -1e30f;
  if (t.i1 == mi) t.v1 = -1e30f;
  if (t.i2 == mi) t.v2 = -1e30f;
  if (t.i3 == mi) t.v3 = -1e30f;
  if (t.i4 == mi) t.v4 = -1e30f;
  if (t.i5 == mi) t.v5 = -1e30f;
}

// ---------------- threshold pass: exact 6th-largest over SAMP-sample, wave per row
__global__ __launch_bounds__(256) void k_thresh(const float* __restrict__ hn,
                                                float* __restrict__ tau, int N) {
  int wave = threadIdx.x >> 6, lane = threadIdx.x & 63;
  int row = blockIdx.x * 4 + wave;
  const float4* hn4 = (const float4*)hn;
  float4 q[4];
#pragma unroll
  for (int m = 0; m < 4; ++m) q[m] = hn4[(size_t)row*4 + m];
  Top6 t; t6_init(t);
#pragma unroll
  for (int k = 0; k < SAMP/64; ++k) {
    int c = lane + 64*k;
    if (c != row) {
      float4 cv[4];
#pragma unroll
      for (int m = 0; m < 4; ++m) cv[m] = hn4[(size_t)c*4 + m];
      float s = dot16_seq(q, cv);
      t6_insert(t, s, c);
    }
  }
  float last = -1e30f;
  for (int sel = 0; sel < K; ++sel) {
    float cv; int ci;
    t6_best(t, cv, ci);
    float mv = cv; int mi = ci;
#pragma unroll
    for (int m = 1; m < 64; m <<= 1) {
      float ov = __shfl_xor(mv, m);
      int   oi = __shfl_xor(mi, m);
      if (ov > mv || (ov == mv && (unsigned)oi < (unsigned)mi)) { mv = ov; mi = oi; }
    }
    t6_consume(t, mi);
    last = mv;
  }
  if (lane == 0) tau[row] = last;
}

// ---------------- stateless threshold scan: 64 rows x 512 cols per block ----
// 2 candidates/lane in NAMED float4s, pinned to VGPRs by asm anchors so the
// compiler cannot sink the loads into the row loop (R5 failure mode).
// Queries: wave-uniform scalar loads (SGPR broadcast).
#define DOT16(S, C0, C1, C2, C3)                                   \
  S = fmaf(q0,  C0.x, S); S = fmaf(q1,  C0.y, S);                  \
  S = fmaf(q2,  C0.z, S); S = fmaf(q3,  C0.w, S);                  \
  S = fmaf(q4,  C1.x, S); S = fmaf(q5,  C1.y, S);                  \
  S = fmaf(q6,  C1.z, S); S = fmaf(q7,  C1.w, S);                  \
  S = fmaf(q8,  C2.x, S); S = fmaf(q9,  C2.y, S);                  \
  S = fmaf(q10, C2.z, S); S = fmaf(q11, C2.w, S);                  \
  S = fmaf(q12, C3.x, S); S = fmaf(q13, C3.y, S);                  \
  S = fmaf(q14, C3.z, S); S = fmaf(q15, C3.w, S);

__global__ __launch_bounds__(256) void k_scan2(
    const float* __restrict__ hn, const float* __restrict__ tau,
    int* __restrict__ cnt, unsigned short* __restrict__ buf, int N) {
  int ib = blockIdx.x >> 4;          // row-block of 64 rows (N/64 of them)
  int jc = blockIdx.x & 15;          // col-chunk of 512
  int ibase = ib * 64;
  int wave = threadIdx.x >> 6, lane = threadIdx.x & 63;
  const float4* hn4 = (const float4*)hn;

  int jb = jc*512 + wave*128 + lane;   // lane's cands: jb, jb+64
  float4 cA0 = hn4[(size_t)(jb     )*4+0], cA1 = hn4[(size_t)(jb     )*4+1],
         cA2 = hn4[(size_t)(jb     )*4+2], cA3 = hn4[(size_t)(jb     )*4+3];
  float4 cB0 = hn4[(size_t)(jb + 64)*4+0], cB1 = hn4[(size_t)(jb + 64)*4+1],
         cB2 = hn4[(size_t)(jb + 64)*4+2], cB3 = hn4[(size_t)(jb + 64)*4+3];
  // pin all 32 components to VGPRs (loads feed opaque asm -> cannot be sunk)
  asm volatile("" : "+v"(cA0.x), "+v"(cA0.y), "+v"(cA0.z), "+v"(cA0.w),
                    "+v"(cA1.x), "+v"(cA1.y), "+v"(cA1.z), "+v"(cA1.w),
                    "+v"(cA2.x), "+v"(cA2.y), "+v"(cA2.z), "+v"(cA2.w),
                    "+v"(cA3.x), "+v"(cA3.y), "+v"(cA3.z), "+v"(cA3.w));
  asm volatile("" : "+v"(cB0.x), "+v"(cB0.y), "+v"(cB0.z), "+v"(cB0.w),
                    "+v"(cB1.x), "+v"(cB1.y), "+v"(cB1.z), "+v"(cB1.w),
                    "+v"(cB2.x), "+v"(cB2.y), "+v"(cB2.z), "+v"(cB2.w),
                    "+v"(cB3.x), "+v"(cB3.y), "+v"(cB3.z), "+v"(cB3.w));

#pragma unroll 2
  for (int ii = 0; ii < 64; ++ii) {
    int ig = ibase + ii;
    const float* qp = hn + (size_t)ig * HP;   // uniform -> s_load
    float tau_i = tau[ig];                    // uniform -> s_load
    float q0 = qp[0],  q1 = qp[1],  q2 = qp[2],  q3 = qp[3],
          q4 = qp[4],  q5 = qp[5],  q6 = qp[6],  q7 = qp[7],
          q8 = qp[8],  q9 = qp[9],  q10 = qp[10], q11 = qp[11],
          q12 = qp[12], q13 = qp[13], q14 = qp[14], q15 = qp[15];
    float sA = 0.f, sB = 0.f;
    DOT16(sA, cA0, cA1, cA2, cA3)
    DOT16(sB, cB0, cB1, cB2, cB3)
    // self-hit allowed (s_ii≈1>=tau); k_final filters j==row
    if (sA >= tau_i) {
      int pos = atomicAdd(&cnt[ig], 1);
      if (pos < CAP) buf[(size_t)ig*CAP + pos] = (unsigned short)jb;
    }
    if (sB >= tau_i) {
      int pos = atomicAdd(&cnt[ig], 1);
      if (pos < CAP) buf[(size_t)ig*CAP + pos] = (unsigned short)(jb + 64);
    }
  }
}

// ---------------- exact top-6 from buffered candidates, wave per row ----
__global__ __launch_bounds__(256) void k_final(
    const float* __restrict__ hn, const unsigned short* __restrict__ buf,
    const int* __restrict__ cnt,
    float* __restrict__ evals, int* __restrict__ eidx,
    float* __restrict__ ownsum, float* insum, int* indeg, int N) {
  int wave = threadIdx.x >> 6, lane = threadIdx.x & 63;
  int row = blockIdx.x * 4 + wave;
  const float4* hn4 = (const float4*)hn;
  float4 q[4];
#pragma unroll
  for (int m = 0; m < 4; ++m) q[m] = hn4[(size_t)row*4 + m];
  int n = min(cnt[row], CAP);
  Top6 t; t6_init(t);
  for (int e = lane; e < n; e += 64) {
    int j = buf[(size_t)row*CAP + e];
    if (j != row) {
      float4 cv[4];
#pragma unroll
      for (int m = 0; m < 4; ++m) cv[m] = hn4[(size_t)j*4 + m];
      float s = dot16_seq(q, cv);
      t6_insert(t, s, j);
    }
  }
  float osum = 0.f;
  for (int sel = 0; sel < K; ++sel) {
    float cv; int ci;
    t6_best(t, cv, ci);
    float mv = cv; int mi = ci;
#pragma unroll
    for (int m = 1; m < 64; m <<= 1) {
      float ov = __shfl_xor(mv, m);
      int   oi = __shfl_xor(mi, m);
      if (ov > mv || (ov == mv && (unsigned)oi < (unsigned)mi)) { mv = ov; mi = oi; }
    }
    t6_consume(t, mi);
    if (lane == 0) {
      evals[row*K + sel] = mv;
      eidx [row*K + sel] = mi;
      osum += mv;
      atomicAdd(&insum[mi], mv);
      atomicAdd(&indeg[mi], 1);
    }
  }
  if (lane == 0) ownsum[row] = osum;
}

// ------- fused: degree scalars + exclusive scan of (K + indeg) -> CSR offsets ----
__global__ __launch_bounds__(1024) void k_scan(
    const int* __restrict__ indeg, const float* __restrict__ ownsum,
    const float* __restrict__ insum,
    float* __restrict__ rnorm, float* __restrict__ dinv, float* __restrict__ selfc,
    int* __restrict__ cursor, int* __restrict__ offsets, int N) {
  __shared__ int sums[1024];
  int tid = threadIdx.x;
  int per = N >> 10;           // assumes N multiple of 1024
  int base = tid * per;
  int loc[16];
  int s = 0;
  for (int k = 0; k < per; ++k) {
    int i = base + k;
    float rs = 0.5f * (ownsum[i] + insum[i]);
    float rn = 1.f / (rs + 1e-8f);
    float ds = 1.f + rs * rn;
    float di = rsqrtf(fmaxf(ds, 1e-12f));
    rnorm[i] = rn; dinv[i] = di; selfc[i] = di * di; cursor[i] = 0;
    loc[k] = s; s += K + indeg[i];
  }
  sums[tid] = s;
  __syncthreads();
  for (int d = 1; d < 1024; d <<= 1) {
    int v = (tid >= d) ? sums[tid - d] : 0;
    __syncthreads();
    sums[tid] += v;
    __syncthreads();
  }
  int excl = (tid == 0) ? 0 : sums[tid - 1];
  for (int k = 0; k < per; ++k) offsets[base + k] = excl + loc[k];
  if (tid == 1023) offsets[N] = sums[1023];
}

// ---------------- fill symmetrized CSR with fused coefficients ----------------
__global__ void k_fill(const float* __restrict__ evals, const int* __restrict__ eidx,
                       const float* __restrict__ rnorm, const float* __restrict__ dinv,
                       const int* __restrict__ offsets, int* cursor,
                       int* __restrict__ col, float* __restrict__ coef, int N) {
  int e = blockIdx.x * blockDim.x + threadIdx.x;
  if (e >= N * K) return;
  int i = e / K;
  int j = eidx[e];
  float v = evals[e];
  float base = 0.5f * v * dinv[i] * dinv[j];
  int p = atomicAdd(&cursor[i], 1);
  col [offsets[i] + p] = j;
  coef[offsets[i] + p] = base * rnorm[i];
  int q = atomicAdd(&cursor[j], 1);
  col [offsets[j] + q] = i;
  coef[offsets[j] + q] = base * rnorm[j];
}

// ---------------- dense h @ W ----------------
template<int DIN, int DOUT>
__global__ void k_xw(const float* __restrict__ h, const float* __restrict__ W,
                     float* __restrict__ XW, int N) {
  int gid = blockIdx.x * blockDim.x + threadIdx.x;
  if (gid >= N * DOUT) return;
  int oc = gid % DOUT;
  int i  = gid / DOUT;
  float acc = 0.f;
#pragma unroll
  for (int d = 0; d < DIN; ++d) acc += h[i*DIN + d] * W[d*DOUT + oc];
  XW[gid] = acc;
}

// ---------------- fused: sparse gather + bias + LN + relu + MLP residual ----------------
template<int DIN, int HID, int DOUT>
__global__ __launch_bounds__(256) void k_gpost(
    const float* __restrict__ XW, const int* __restrict__ offsets,
    const int* __restrict__ col, const float* __restrict__ coef,
    const float* __restrict__ selfc,
    const float* __restrict__ b, const float* __restrict__ g, const float* __restrict__ bt,
    const float* __restrict__ hprev,
    const float* __restrict__ w0, const float* __restrict__ b0,
    const float* __restrict__ w1, const float* __restrict__ b1,
    float* __restrict__ out, int N) {
  __shared__ float hid_s[4][HID];
  int wslot = threadIdx.x >> 6;
  int row   = (blockIdx.x * blockDim.x + threadIdx.x) >> 6;
  int lane  = threadIdx.x & 63;
  int o0 = lane, o1 = lane + 64;

  float sc = selfc[row];
  float acc0 = 0.f, acc1 = 0.f;
  if (o0 < DOUT)  acc0 = sc * XW[(size_t)row*DOUT + o0];
  if (DOUT > 64)  acc1 = sc * XW[(size_t)row*DOUT + o1];
  int pe = offsets[row + 1];
  for (int p = offsets[row]; p < pe; ++p) {
    int jj = col[p]; float cf = coef[p];
    if (o0 < DOUT) acc0 += cf * XW[(size_t)jj*DOUT + o0];
    if (DOUT > 64) acc1 += cf * XW[(size_t)jj*DOUT + o1];
  }
  float u0 = (o0 < DOUT) ? acc0 + b[o0] : 0.f;
  float u1 = (DOUT > 64) ? acc1 + b[o1] : 0.f;

  float s = u0 + u1;
#pragma unroll
  for (int m = 1; m < 64; m <<= 1) s += __shfl_xor(s, m);
  float mean = s / (float)DOUT;
  float d0 = (o0 < DOUT) ? u0 - mean : 0.f;
  float d1 = (DOUT > 64) ? u1 - mean : 0.f;
  float vs = d0*d0 + d1*d1;
#pragma unroll
  for (int m = 1; m < 64; m <<= 1) vs += __shfl_xor(vs, m);
  float rstd = rsqrtf(vs / (float)DOUT + 1e-5f);
  float t0 = (o0 < DOUT) ? fmaxf(d0*rstd*g[o0] + bt[o0], 0.f) : 0.f;
  float t1 = (DOUT > 64) ? fmaxf(d1*rstd*g[o1] + bt[o1], 0.f) : 0.f;

  // MLP hidden = relu(hprev @ w0 + b0), staged in LDS per wave
  float hp[DIN];
#pragma unroll
  for (int d = 0; d < DIN; ++d) hp[d] = hprev[(size_t)row*DIN + d];
  if (lane < HID) {
    float a = b0[lane];
#pragma unroll
    for (int d = 0; d < DIN; ++d) a += hp[d] * w0[d*HID + lane];
    hid_s[wslot][lane] = fmaxf(a, 0.f);
  }
  if (HID > 64) {
    int h2i = lane + 64;
    float a = b0[h2i];
#pragma unroll
    for (int d = 0; d < DIN; ++d) a += hp[d] * w0[d*HID + h2i];
    hid_s[wslot][h2i] = fmaxf(a, 0.f);
  }
  __syncthreads();

  if (o0 < DOUT) {
    float a = b1[o0];
    for (int h = 0; h < HID; ++h) a += hid_s[wslot][h] * w1[h*DOUT + o0];
    out[(size_t)row*DOUT + o0] = t0 + a;
  }
  if (DOUT > 64) {
    float a = b1[o1];
    for (int h = 0; h < HID; ++h) a += hid_s[wslot][h] * w1[h*DOUT + o1];
    out[(size_t)row*DOUT + o1] = t1 + a;
  }
}

extern "C" void kernel_launch(void* const* d_in, const int* in_sizes, int n_in,
                              void* d_out, int out_size, void* d_ws, size_t ws_size,
                              hipStream_t stream) {
  const float* x    = (const float*)d_in[0];
  const float* Wp   = (const float*)d_in[1];
  const float* bp   = (const float*)d_in[2];
  const float* gw0  = (const float*)d_in[3];
  const float* gb0  = (const float*)d_in[4];
  const float* gw1  = (const float*)d_in[5];
  const float* gb1  = (const float*)d_in[6];
  const float* gw2  = (const float*)d_in[7];
  const float* gb2  = (const float*)d_in[8];
  const float* lg0  = (const float*)d_in[9];
  const float* lb0  = (const float*)d_in[10];
  const float* lg1  = (const float*)d_in[11];
  const float* lb1  = (const float*)d_in[12];
  const float* lg2  = (const float*)d_in[13];
  const float* lb2  = (const float*)d_in[14];
  const float* riw0 = (const float*)d_in[15];
  const float* rib0 = (const float*)d_in[16];
  const float* riw1 = (const float*)d_in[17];
  const float* rib1 = (const float*)d_in[18];
  const float* rhw0 = (const float*)d_in[19];
  const float* rhb0 = (const float*)d_in[20];
  const float* rhw1 = (const float*)d_in[21];
  const float* rhb1 = (const float*)d_in[22];
  const float* row0 = (const float*)d_in[23];
  const float* rob0 = (const float*)d_in[24];
  const float* row1 = (const float*)d_in[25];
  const float* rob1 = (const float*)d_in[26];
  int N = in_sizes[0] / D_IN;   // 8192
  float* out = (float*)d_out;

  char* ws = (char*)d_ws;
  size_t off = 0;
  auto alloc = [&](size_t bytes) -> void* {
    void* p = ws + off;
    off += (bytes + 255) & ~(size_t)255;
    return p;
  };
  float* hn      = (float*)alloc((size_t)N * HP * 4);
  float* evals   = (float*)alloc((size_t)N * K * 4);
  int*   eidx    = (int*)  alloc((size_t)N * K * 4);
  float* ownsum  = (float*)alloc((size_t)N * 4);
  float* insum   = (float*)alloc((size_t)N * 4);
  int*   indeg   = (int*)  alloc((size_t)N * 4);
  float* rnorm   = (float*)alloc((size_t)N * 4);
  float* dinv    = (float*)alloc((size_t)N * 4);
  float* selfc   = (float*)alloc((size_t)N * 4);
  int*   offsets = (int*)  alloc((size_t)(N + 1) * 4);
  int*   cursor  = (int*)  alloc((size_t)N * 4);
  int*   colA    = (int*)  alloc((size_t)N * K * 2 * 4);
  float* coefA   = (float*)alloc((size_t)N * K * 2 * 4);
  float* XW      = (float*)alloc((size_t)N * 128 * 4);
  float* h1      = (float*)alloc((size_t)N * 32 * 4);
  float* h2      = (float*)alloc((size_t)N * 32 * 4);
  float* tau     = (float*)alloc((size_t)N * 4);
  int*   cnt     = (int*)  alloc((size_t)N * 4);
  unsigned short* buf = (unsigned short*)alloc((size_t)N * CAP * 2);
  (void)ws_size; (void)n_in; (void)out_size;

  const int B = 256;
  hipLaunchKernelGGL(k_proj, dim3((N + B - 1) / B), dim3(B), 0, stream,
                     x, Wp, bp, hn, insum, indeg, cnt, N);
  hipLaunchKernelGGL(k_thresh, dim3(N / 4), dim3(B), 0, stream, hn, tau, N);
  // (N/64) row-blocks x 16 col-chunks of 512
  hipLaunchKernelGGL(k_scan2, dim3((N / 64) * 16), dim3(B), 0, stream, hn, tau, cnt, buf, N);
  hipLaunchKernelGGL(k_final, dim3(N / 4), dim3(B), 0, stream,
                     hn, buf, cnt, evals, eidx, ownsum, insum, indeg, N);
  hipLaunchKernelGGL(k_scan, dim3(1), dim3(1024), 0, stream,
                     indeg, ownsum, insum, rnorm, dinv, selfc, cursor, offsets, N);
  hipLaunchKernelGGL(k_fill, dim3((N * K + B - 1) / B), dim3(B), 0, stream,
                     evals, eidx, rnorm, dinv, offsets, cursor, colA, coefA, N);

  // layer 0: x[20] -> 32
  hipLaunchKernelGGL((k_xw<20, 32>), dim3((N * 32 + B - 1) / B), dim3(B), 0, stream, x, gw0, XW, N);
  hipLaunchKernelGGL((k_gpost<20, 32, 32>), dim3(N / 4), dim3(B), 0, stream,
                     XW, offsets, colA, coefA, selfc, gb0, lg0, lb0,
                     x, riw0, rib0, riw1, rib1, h1, N);
  // layer 1: h1[32] -> 32
  hipLaunchKernelGGL((k_xw<32, 32>), dim3((N * 32 + B - 1) / B), dim3(B), 0, stream, h1, gw1, XW, N);
  hipLaunchKernelGGL((k_gpost<32, 32, 32>), dim3(N / 4), dim3(B), 0, stream,
                     XW, offsets, colA, coefA, selfc, gb1, lg1, lb1,
                     h1, rhw0, rhb0, rhw1, rhb1, h2, N);
  // layer 2: h2[32] -> 128
  hipLaunchKernelGGL((k_xw<32, 128>), dim3((N * 128 + B - 1) / B), dim3(B), 0, stream, h2, gw2, XW, N);
  hipLaunchKernelGGL((k_gpost<32, 128, 128>), dim3(N / 4), dim3(B), 0, stream,
                     XW, offsets, colA, coefA, selfc, gb2, lg2, lb2,
                     h2, row0, rob0, row1, rob1, out, N);
}